// Round 3
// baseline (3441.256 us; speedup 1.0000x reference)
//
#include <hip/hip_runtime.h>
#include <math.h>

#define BATCH 8
#define WID   32
#define NX    64
#define NY    64
#define NT    40
#define M1C   12
#define KT    8      // M3
#define KXC   24
#define KYC   24
#define NXY   (NX*NY)        // 4096
#define NXYT  (NXY*NT)       // 163840
#define NP    (BATCH*NXYT)   // 1310720

#define TWO_PI 6.283185307179586f

static __device__ __forceinline__ float gelu_f(float v){
  return 0.5f*v*(1.0f + erff(v*0.7071067811865476f));
}

// barrier that does NOT drain vmcnt (keeps global prefetch loads in flight).
// LDS cross-thread deps are covered by lgkmcnt(0).
static __device__ __forceinline__ void barrier_lds(){
  asm volatile("s_waitcnt lgkmcnt(0)\n\ts_barrier" ::: "memory");
}

// ---------------- fc0: [B,X,Y,T,5] -> V [B,32,X,Y,T] ----------------
__global__ __launch_bounds__(256) void k_fc0(const float* __restrict__ h, const float* __restrict__ x,
                                             const float* __restrict__ w, const float* __restrict__ b,
                                             float* __restrict__ V){
  int p = blockIdx.x*256 + threadIdx.x;
  if(p >= NP) return;
  int bi = p / NXYT, xyt = p - bi*NXYT;
  float i0 = h[(size_t)p*2+0], i1 = h[(size_t)p*2+1];
  float i2 = x[(size_t)p*3+0], i3 = x[(size_t)p*3+1], i4 = x[(size_t)p*3+2];
  #pragma unroll
  for(int c=0;c<WID;c++){
    float v = b[c] + i0*w[c] + i1*w[32+c] + i2*w[64+c] + i3*w[96+c] + i4*w[128+c];
    V[((size_t)(bi*WID+c))*NXYT + xyt] = v;
  }
}

// ------- fused forward T+Y: V[b,c,x,:,:] -> F2 [bc*64+x][ky*8+kt] -------
__global__ __launch_bounds__(256) void k_fwd_ty(const float* __restrict__ V, float2* __restrict__ F2){
  __shared__ float  vt[NY*NT];          // 2560 floats
  __shared__ float2 f1[NY*KT];          // 512 cplx
  __shared__ float  tc[KT*NT], ts[KT*NT];
  __shared__ float  yc[KYC*65], ys[KYC*65];   // stride 65: break 8-way conflict
  int tid = threadIdx.x;
  size_t base = (size_t)blockIdx.x * (NY*NT);
  for(int i=tid;i<NY*NT;i+=256) vt[i] = V[base + i];
  for(int i=tid;i<KT*NT;i+=256){
    int k=i/NT, t=i-k*NT;
    float ang = -TWO_PI*(float)((k*t)%NT)/(float)NT;
    tc[i]=cosf(ang); ts[i]=sinf(ang);
  }
  for(int i=tid;i<KYC*NY;i+=256){
    int ky=i/NY, y=i-ky*NY;
    int f = ky<M1C ? ky : ky+40;
    float ang = -TWO_PI*(float)((f*y)%NY)/(float)NY;
    yc[ky*65+y]=cosf(ang); ys[ky*65+y]=sinf(ang);
  }
  __syncthreads();
  for(int item=tid; item<NY*KT; item+=256){
    int y=item>>3, k=item&7;
    float sr=0.f, si=0.f;
    #pragma unroll
    for(int t=0;t<NT;t++){ float v=vt[y*NT+t]; sr+=v*tc[k*NT+t]; si+=v*ts[k*NT+t]; }
    f1[item]=make_float2(sr,si);
  }
  __syncthreads();
  if(tid < KYC*KT){
    int ky=tid>>3, kt=tid&7;
    float sr=0.f, si=0.f;
    #pragma unroll 8
    for(int y=0;y<NY;y++){
      float2 a=f1[y*KT+kt];
      float c=yc[ky*65+y], s=ys[ky*65+y];
      sr += a.x*c - a.y*s;
      si += a.x*s + a.y*c;
    }
    F2[(size_t)blockIdx.x*(KYC*KT) + tid] = make_float2(sr,si);
  }
}

// ---------------- forward X: F2 -> F3 [B,32,24,24,8] cplx ----------------
__global__ __launch_bounds__(256) void k_fwd_x(const float2* __restrict__ F2, float2* __restrict__ F3){
  __shared__ float2 tile[NX*KT];
  __shared__ float twc[KXC*65], tws[KXC*65];   // stride 65
  int tid=threadIdx.x;
  int bc = blockIdx.x / KYC;                 // [0,256)
  int ky = blockIdx.x - bc*KYC;
  for(int i=tid;i<NX*KT;i+=256){
    int xx=i/KT, kt=i-xx*KT;
    tile[i] = F2[((size_t)bc*NX + xx)*(KYC*KT) + ky*KT + kt];
  }
  for(int i=tid;i<KXC*NX;i+=256){
    int kx=i/NX, xx=i-kx*NX;
    int f = kx<M1C ? kx : kx+40;
    float ang = -TWO_PI*(float)((f*xx)%NX)/(float)NX;
    twc[kx*65+xx]=cosf(ang); tws[kx*65+xx]=sinf(ang);
  }
  __syncthreads();
  for(int item=tid; item<KXC*KT; item+=256){
    int kx=item/KT, kt=item-kx*KT;
    float sr=0.f, si=0.f;
    #pragma unroll 8
    for(int xx=0;xx<NX;xx++){
      float2 a = tile[xx*KT+kt];
      float c = twc[kx*65+xx], s = tws[kx*65+xx];
      sr += a.x*c - a.y*s;
      si += a.x*s + a.y*c;
    }
    F3[(size_t)bc*(KXC*KYC*KT) + kx*(KYC*KT) + ky*KT + kt] = make_float2(sr,si);
  }
}

// ---------------- channel mix: F3 -> F4 ----------------
__global__ __launch_bounds__(256) void k_mix(const float2* __restrict__ F3, const float* __restrict__ wr,
                                             const float* __restrict__ wi, float2* __restrict__ F4){
  int idx = blockIdx.x*256 + threadIdx.x;    // < 8*32*4608
  int b = idx / (WID*4608);
  int r = idx - b*(WID*4608);
  int o = r / 4608;
  int mode = r - o*4608;
  int kx = mode/192;
  int ky = (mode/KT)%KYC;
  int xp = (kx>=M1C), yp = (ky>=M1C);
  int m1 = kx - M1C*xp, m2 = ky - M1C*yp;
  int blk = xp + 2*yp;
  int kt = mode & 7;
  size_t widx = (size_t)blk*1179648 + (size_t)o*1152 + m1*96 + m2*8 + kt;
  const float2* src = F3 + (size_t)b*WID*4608 + mode;
  float ar=0.f, ai=0.f;
  #pragma unroll 8
  for(int i=0;i<WID;i++){
    float2 a = src[(size_t)i*4608];
    float r_ = wr[widx], q_ = wi[widx];
    ar += a.x*r_ - a.y*q_;
    ai += a.x*q_ + a.y*r_;
    widx += 36864;
  }
  F4[((size_t)b*WID + o)*4608 + mode] = make_float2(ar, ai);
}

// ---------------- inverse X: F4 -> F2 (1/64 folded) ----------------
__global__ __launch_bounds__(256) void k_inv_x(const float2* __restrict__ F4, float2* __restrict__ F2){
  __shared__ float2 tile[KXC*KT];
  __shared__ float twc[NX*KXC], tws[NX*KXC];
  int tid=threadIdx.x;
  int bc = blockIdx.x / KYC, ky = blockIdx.x - (blockIdx.x/KYC)*KYC;
  for(int i=tid;i<KXC*KT;i+=256){
    int kx=i/KT, kt=i-kx*KT;
    tile[i] = F4[(size_t)bc*4608 + kx*(KYC*KT) + ky*KT + kt];
  }
  for(int i=tid;i<NX*KXC;i+=256){
    int xx=i/KXC, kx=i-xx*KXC;
    int f = kx<M1C ? kx : kx+40;
    float ang = TWO_PI*(float)((f*xx)%NX)/(float)NX;
    twc[i]=cosf(ang)*(1.0f/64.0f); tws[i]=sinf(ang)*(1.0f/64.0f);
  }
  __syncthreads();
  for(int item=tid; item<NX*KT; item+=256){
    int xx=item/KT, kt=item-xx*KT;
    float sr=0.f, si=0.f;
    #pragma unroll 8
    for(int kx=0;kx<KXC;kx++){
      float2 a = tile[kx*KT+kt];
      float c = twc[xx*KXC+kx], s = tws[xx*KXC+kx];
      sr += a.x*c - a.y*s;
      si += a.x*s + a.y*c;
    }
    F2[((size_t)bc*NX + xx)*(KYC*KT) + ky*KT + kt] = make_float2(sr,si);
  }
}

// ------- fused inv-Y + irfft-T + conv1x1 [+gelu], in-place on V -------
// one block per (b,x); loops y = 0..63.
// F2 slice held in REGISTERS (thread=(c,kt): 24 cplx). wm row in registers
// (thread=(o,tg)). vt double-buffered in LDS, transposed [t][c] pad-36.
#define VTS 36
template<bool GELU>
__global__ __launch_bounds__(256,3) void k_inv_y_conv(const float2* __restrict__ F2, const float* __restrict__ wcv,
                                                      const float* __restrict__ bcv, float* __restrict__ Vio){
  __shared__ float2 twy[NY*KYC];       // 12 KB, 1/64 folded
  __shared__ float2 tcts[KT*NT];       // 2.5 KB, w_k/40 folded
  __shared__ float2 ftc[256];          // [kt][c] -> kt*32+c
  __shared__ __align__(16) float vtT[2][NT*VTS]; // transposed vt, 2 buffers
  int tid = threadIdx.x;
  int b = blockIdx.x >> 6, x = blockIdx.x & 63;
  int cid = tid & 31, ktid = tid >> 5;     // inv-Y identity
  int oid = tid & 31, tg  = tid >> 5;      // conv identity; t = tg*5 + j

  // --- one-time init ---
  for(int i=tid;i<NY*KYC;i+=256){
    int y=i/KYC, ky=i-y*KYC;
    int f = ky<M1C ? ky : ky+40;
    float ang = TWO_PI*(float)((f*y)%NY)/(float)NY;
    twy[i] = make_float2(cosf(ang)*(1.0f/64.0f), sinf(ang)*(1.0f/64.0f));
  }
  for(int i=tid;i<KT*NT;i+=256){
    int k=i/NT, t=i-k*NT;
    float ang = TWO_PI*(float)((k*t)%NT)/(float)NT;
    float sc = (k==0 ? 1.0f : 2.0f)*(1.0f/(float)NT);
    tcts[i] = make_float2(cosf(ang)*sc, sinf(ang)*sc);
  }
  // F2 slice -> registers: fr[ky] for this (cid,ktid)
  float2 fr[KYC];
  {
    const float2* fp = F2 + ((size_t)(b*WID+cid)*NX + x)*(KYC*KT) + ktid;
    #pragma unroll
    for(int ky=0;ky<KYC;ky++) fr[ky] = fp[ky*KT];
  }
  // wm row -> registers
  float wreg[WID];
  #pragma unroll
  for(int c=0;c<WID;c++) wreg[c] = wcv[oid*WID + c];
  float breg = bcv[oid];

  // vt chunk identities: 320 float4-chunks, chunk i: c=i/10, tq=i%10
  int ch0 = tid;            int cc0 = ch0/10, tq0 = ch0 - cc0*10;
  int ch1 = 256 + tid;      int cc1 = ch1/10, tq1 = ch1 - cc1*10;  // only tid<64
  const float4* gb0 = (const float4*)(Vio + ((size_t)(b*WID+cc0)*NXY + x*NY)*NT) + tq0;
  const float4* gb1 = (const float4*)(Vio + ((size_t)(b*WID+cc1)*NXY + x*NY)*NT) + tq1;
  bool has2 = tid < 64;

  // prologue: vt(y=0) -> buf0
  float4 g0 = gb0[0];
  float4 g1 = has2 ? gb1[0] : make_float4(0,0,0,0);
  {
    float* d = &vtT[0][0];
    d[(tq0*4+0)*VTS+cc0]=g0.x; d[(tq0*4+1)*VTS+cc0]=g0.y; d[(tq0*4+2)*VTS+cc0]=g0.z; d[(tq0*4+3)*VTS+cc0]=g0.w;
    if(has2){ d[(tq1*4+0)*VTS+cc1]=g1.x; d[(tq1*4+1)*VTS+cc1]=g1.y; d[(tq1*4+2)*VTS+cc1]=g1.z; d[(tq1*4+3)*VTS+cc1]=g1.w; }
  }
  barrier_lds();

  float* outrow = Vio + ((size_t)(b*WID+oid)*NXY + x*NY)*NT + tg*5;

  for(int y=0;y<NY;y++){
    // prefetch vt(y+1) into registers (stays in flight across the barrier)
    if(y+1 < NY){
      g0 = gb0[(size_t)(y+1)*10];
      if(has2) g1 = gb1[(size_t)(y+1)*10];
    }
    // inv-Y in registers -> ftc
    {
      const float2* tw = &twy[y*KYC];
      float sr=0.f, si=0.f;
      #pragma unroll
      for(int ky=0;ky<KYC;ky++){
        float2 w = tw[ky];          // broadcast read
        float2 a = fr[ky];
        sr += a.x*w.x - a.y*w.y;
        si += a.x*w.y + a.y*w.x;
      }
      ftc[ktid*32 + cid] = make_float2(sr,si);
    }
    barrier_lds();
    // conv + irfft-T
    {
      float2 fR[KT];
      #pragma unroll
      for(int k=0;k<KT;k++) fR[k] = ftc[k*32 + oid];
      const float* vb = &vtT[y&1][0];
      float acc[5];
      #pragma unroll
      for(int j=0;j<5;j++){
        int t = tg*5 + j;
        float a = breg;
        const float* vrow = vb + t*VTS;
        #pragma unroll
        for(int c4=0;c4<WID;c4+=4){
          float4 vv = *(const float4*)(vrow + c4);   // broadcast b128
          a += vv.x*wreg[c4] + vv.y*wreg[c4+1] + vv.z*wreg[c4+2] + vv.w*wreg[c4+3];
        }
        #pragma unroll
        for(int k=0;k<KT;k++){
          float2 w = tcts[k*NT + t];
          a += fR[k].x*w.x - fR[k].y*w.y;
        }
        acc[j] = GELU ? gelu_f(a) : a;
      }
      float* op = outrow + (size_t)y*NT;
      #pragma unroll
      for(int j=0;j<5;j++) op[j] = acc[j];
    }
    // write prefetched vt(y+1) into the other buffer
    if(y+1 < NY){
      float* d = &vtT[(y+1)&1][0];
      d[(tq0*4+0)*VTS+cc0]=g0.x; d[(tq0*4+1)*VTS+cc0]=g0.y; d[(tq0*4+2)*VTS+cc0]=g0.z; d[(tq0*4+3)*VTS+cc0]=g0.w;
      if(has2){ d[(tq1*4+0)*VTS+cc1]=g1.x; d[(tq1*4+1)*VTS+cc1]=g1.y; d[(tq1*4+2)*VTS+cc1]=g1.z; d[(tq1*4+3)*VTS+cc1]=g1.w; }
    }
    barrier_lds();
  }
}

// ---------------- fused fc1+gelu+fc2: V -> out [B,X,Y,T,2] ----------------
__global__ __launch_bounds__(64) void k_mlp(const float* __restrict__ Vin, const float* __restrict__ w1,
                                            const float* __restrict__ b1, const float* __restrict__ w2,
                                            const float* __restrict__ b2, float* __restrict__ out){
  __shared__ float vt[WID*NT];
  __shared__ float sw1[WID*64];
  __shared__ float sb1[64];
  __shared__ float sw2[128];
  __shared__ float sb2[2];
  int tid=threadIdx.x;
  int b  = blockIdx.x >> 12;
  int xy = blockIdx.x & 4095;
  for(int i=tid;i<WID*NT;i+=64){
    int c=i/NT, t=i-c*NT;
    vt[i] = Vin[((size_t)(b*WID+c))*NXYT + xy*NT + t];
  }
  for(int i=tid;i<WID*64;i+=64) sw1[i]=w1[i];
  sb1[tid]=b1[tid];
  for(int i=tid;i<128;i+=64) sw2[i]=w2[i];
  if(tid<2) sb2[tid]=b2[tid];
  __syncthreads();
  if(tid<NT){
    float vcol[WID];
    #pragma unroll
    for(int c=0;c<WID;c++) vcol[c]=vt[c*NT+tid];
    float o0=sb2[0], o1=sb2[1];
    #pragma unroll 4
    for(int j=0;j<64;j++){
      float a = sb1[j];
      #pragma unroll
      for(int c=0;c<WID;c++) a += vcol[c]*sw1[c*64+j];
      a = gelu_f(a);
      o0 += a*sw2[j*2+0];
      o1 += a*sw2[j*2+1];
    }
    size_t p = ((size_t)(b*NXY + xy))*NT + tid;
    out[p*2+0]=o0;
    out[p*2+1]=o1;
  }
}

extern "C" void kernel_launch(void* const* d_in, const int* in_sizes, int n_in,
                              void* d_out, int out_size, void* d_ws, size_t ws_size,
                              hipStream_t stream){
  const float* h     = (const float*)d_in[0];
  const float* x     = (const float*)d_in[1];
  const float* fc0_w = (const float*)d_in[2];
  const float* fc0_b = (const float*)d_in[3];
  const float* scwr[3] = {(const float*)d_in[4], (const float*)d_in[6], (const float*)d_in[8]};
  const float* scwi[3] = {(const float*)d_in[5], (const float*)d_in[7], (const float*)d_in[9]};
  const float* cw[3]   = {(const float*)d_in[10], (const float*)d_in[12], (const float*)d_in[14]};
  const float* cb[3]   = {(const float*)d_in[11], (const float*)d_in[13], (const float*)d_in[15]};
  const float* fc1_w = (const float*)d_in[16];
  const float* fc1_b = (const float*)d_in[17];
  const float* fc2_w = (const float*)d_in[18];
  const float* fc2_b = (const float*)d_in[19];

  // workspace: V (167.8 MB) | F2 (25.2 MB) | F4 (9.4 MB)  == 202 MB total
  // F3 lives in d_out (9.4 MB <= 10.5 MB) until k_mlp overwrites it at the end.
  const size_t VSZ = (size_t)BATCH*WID*NXYT;          // 41,943,040 floats
  float*  V  = (float*)d_ws;
  float2* F2 = (float2*)(V + VSZ);                    // B*32*64*24*8 = 3,145,728 cplx
  float2* F4 = F2 + (size_t)BATCH*WID*NX*KYC*KT;      // B*32*24*24*8 = 1,179,648 cplx
  float2* F3 = (float2*)d_out;                        // scratch until final k_mlp

  k_fc0<<<NP/256, 256, 0, stream>>>(h, x, fc0_w, fc0_b, V);
  for(int L=0; L<3; L++){
    k_fwd_ty<<<BATCH*WID*NX, 256, 0, stream>>>(V, F2);
    k_fwd_x<<<(BATCH*WID)*KYC, 256, 0, stream>>>(F2, F3);
    k_mix<<<(BATCH*WID*KXC*KYC*KT)/256, 256, 0, stream>>>(F3, scwr[L], scwi[L], F4);
    k_inv_x<<<(BATCH*WID)*KYC, 256, 0, stream>>>(F4, F2);
    if(L<2) k_inv_y_conv<true ><<<BATCH*NX, 256, 0, stream>>>(F2, cw[L], cb[L], V);
    else    k_inv_y_conv<false><<<BATCH*NX, 256, 0, stream>>>(F2, cw[L], cb[L], V);
  }
  k_mlp<<<BATCH*NXY, 64, 0, stream>>>(V, fc1_w, fc1_b, fc2_w, fc2_b, (float*)d_out);
}

// Round 4
// 2568.967 us; speedup vs baseline: 1.3395x; 1.3395x over previous
//
#include <hip/hip_runtime.h>
#include <math.h>

#define BATCH 8
#define WID   32
#define NX    64
#define NY    64
#define NT    40
#define M1C   12
#define KT    8      // M3
#define KXC   24
#define KYC   24
#define NXY   (NX*NY)        // 4096
#define NXYT  (NXY*NT)       // 163840
#define NP    (BATCH*NXYT)   // 1310720

#define TWO_PI 6.283185307179586f

static __device__ __forceinline__ float gelu_f(float v){
  return 0.5f*v*(1.0f + erff(v*0.7071067811865476f));
}

// barrier that does NOT drain vmcnt (keeps global prefetch loads in flight).
static __device__ __forceinline__ void barrier_lds(){
  asm volatile("s_waitcnt lgkmcnt(0)\n\ts_barrier" ::: "memory");
}

// ---------------- fc0: [B,X,Y,T,5] -> V [B,32,X,Y,T] ----------------
__global__ __launch_bounds__(256) void k_fc0(const float* __restrict__ h, const float* __restrict__ x,
                                             const float* __restrict__ w, const float* __restrict__ b,
                                             float* __restrict__ V){
  int p = blockIdx.x*256 + threadIdx.x;
  if(p >= NP) return;
  int bi = p / NXYT, xyt = p - bi*NXYT;
  float i0 = h[(size_t)p*2+0], i1 = h[(size_t)p*2+1];
  float i2 = x[(size_t)p*3+0], i3 = x[(size_t)p*3+1], i4 = x[(size_t)p*3+2];
  #pragma unroll
  for(int c=0;c<WID;c++){
    float v = b[c] + i0*w[c] + i1*w[32+c] + i2*w[64+c] + i3*w[96+c] + i4*w[128+c];
    V[((size_t)(bi*WID+c))*NXYT + xyt] = v;
  }
}

// ------- fused forward T+Y: V[b,c,x,:,:] -> F2 [bc*64+x][ky*8+kt] -------
__global__ __launch_bounds__(256) void k_fwd_ty(const float* __restrict__ V, float2* __restrict__ F2){
  __shared__ float  vt[NY*NT];          // 2560 floats
  __shared__ float2 f1[NY*KT];          // 512 cplx
  __shared__ float  tc[KT*NT], ts[KT*NT];
  __shared__ float  yc[KYC*65], ys[KYC*65];   // stride 65: break 8-way conflict
  int tid = threadIdx.x;
  size_t base = (size_t)blockIdx.x * (NY*NT);
  for(int i=tid;i<NY*NT;i+=256) vt[i] = V[base + i];
  for(int i=tid;i<KT*NT;i+=256){
    int k=i/NT, t=i-k*NT;
    float ang = -TWO_PI*(float)((k*t)%NT)/(float)NT;
    tc[i]=cosf(ang); ts[i]=sinf(ang);
  }
  for(int i=tid;i<KYC*NY;i+=256){
    int ky=i/NY, y=i-ky*NY;
    int f = ky<M1C ? ky : ky+40;
    float ang = -TWO_PI*(float)((f*y)%NY)/(float)NY;
    yc[ky*65+y]=cosf(ang); ys[ky*65+y]=sinf(ang);
  }
  __syncthreads();
  for(int item=tid; item<NY*KT; item+=256){
    int y=item>>3, k=item&7;
    float sr=0.f, si=0.f;
    #pragma unroll
    for(int t=0;t<NT;t++){ float v=vt[y*NT+t]; sr+=v*tc[k*NT+t]; si+=v*ts[k*NT+t]; }
    f1[item]=make_float2(sr,si);
  }
  __syncthreads();
  if(tid < KYC*KT){
    int ky=tid>>3, kt=tid&7;
    float sr=0.f, si=0.f;
    #pragma unroll 8
    for(int y=0;y<NY;y++){
      float2 a=f1[y*KT+kt];
      float c=yc[ky*65+y], s=ys[ky*65+y];
      sr += a.x*c - a.y*s;
      si += a.x*s + a.y*c;
    }
    F2[(size_t)blockIdx.x*(KYC*KT) + tid] = make_float2(sr,si);
  }
}

// ---------------- forward X: F2 -> F3 [B,32,24,24,8] cplx ----------------
__global__ __launch_bounds__(256) void k_fwd_x(const float2* __restrict__ F2, float2* __restrict__ F3){
  __shared__ float2 tile[NX*KT];
  __shared__ float twc[KXC*65], tws[KXC*65];   // stride 65
  int tid=threadIdx.x;
  int bc = blockIdx.x / KYC;                 // [0,256)
  int ky = blockIdx.x - bc*KYC;
  for(int i=tid;i<NX*KT;i+=256){
    int xx=i/KT, kt=i-xx*KT;
    tile[i] = F2[((size_t)bc*NX + xx)*(KYC*KT) + ky*KT + kt];
  }
  for(int i=tid;i<KXC*NX;i+=256){
    int kx=i/NX, xx=i-kx*NX;
    int f = kx<M1C ? kx : kx+40;
    float ang = -TWO_PI*(float)((f*xx)%NX)/(float)NX;
    twc[kx*65+xx]=cosf(ang); tws[kx*65+xx]=sinf(ang);
  }
  __syncthreads();
  for(int item=tid; item<KXC*KT; item+=256){
    int kx=item/KT, kt=item-kx*KT;
    float sr=0.f, si=0.f;
    #pragma unroll 8
    for(int xx=0;xx<NX;xx++){
      float2 a = tile[xx*KT+kt];
      float c = twc[kx*65+xx], s = tws[kx*65+xx];
      sr += a.x*c - a.y*s;
      si += a.x*s + a.y*c;
    }
    F3[(size_t)bc*(KXC*KYC*KT) + kx*(KYC*KT) + ky*KT + kt] = make_float2(sr,si);
  }
}

// ---------------- channel mix: F3 -> F4 ----------------
__global__ __launch_bounds__(256) void k_mix(const float2* __restrict__ F3, const float* __restrict__ wr,
                                             const float* __restrict__ wi, float2* __restrict__ F4){
  int idx = blockIdx.x*256 + threadIdx.x;    // < 8*32*4608
  int b = idx / (WID*4608);
  int r = idx - b*(WID*4608);
  int o = r / 4608;
  int mode = r - o*4608;
  int kx = mode/192;
  int ky = (mode/KT)%KYC;
  int xp = (kx>=M1C), yp = (ky>=M1C);
  int m1 = kx - M1C*xp, m2 = ky - M1C*yp;
  int blk = xp + 2*yp;
  int kt = mode & 7;
  size_t widx = (size_t)blk*1179648 + (size_t)o*1152 + m1*96 + m2*8 + kt;
  const float2* src = F3 + (size_t)b*WID*4608 + mode;
  float ar=0.f, ai=0.f;
  #pragma unroll 8
  for(int i=0;i<WID;i++){
    float2 a = src[(size_t)i*4608];
    float r_ = wr[widx], q_ = wi[widx];
    ar += a.x*r_ - a.y*q_;
    ai += a.x*q_ + a.y*r_;
    widx += 36864;
  }
  F4[((size_t)b*WID + o)*4608 + mode] = make_float2(ar, ai);
}

// ---------------- inverse X: F4 -> F2 (1/64 folded) ----------------
__global__ __launch_bounds__(256) void k_inv_x(const float2* __restrict__ F4, float2* __restrict__ F2){
  __shared__ float2 tile[KXC*KT];
  __shared__ float twc[NX*KXC], tws[NX*KXC];
  int tid=threadIdx.x;
  int bc = blockIdx.x / KYC, ky = blockIdx.x - (blockIdx.x/KYC)*KYC;
  for(int i=tid;i<KXC*KT;i+=256){
    int kx=i/KT, kt=i-kx*KT;
    tile[i] = F4[(size_t)bc*4608 + kx*(KYC*KT) + ky*KT + kt];
  }
  for(int i=tid;i<NX*KXC;i+=256){
    int xx=i/KXC, kx=i-xx*KXC;
    int f = kx<M1C ? kx : kx+40;
    float ang = TWO_PI*(float)((f*xx)%NX)/(float)NX;
    twc[i]=cosf(ang)*(1.0f/64.0f); tws[i]=sinf(ang)*(1.0f/64.0f);
  }
  __syncthreads();
  for(int item=tid; item<NX*KT; item+=256){
    int xx=item/KT, kt=item-xx*KT;
    float sr=0.f, si=0.f;
    #pragma unroll 8
    for(int kx=0;kx<KXC;kx++){
      float2 a = tile[kx*KT+kt];
      float c = twc[xx*KXC+kx], s = tws[xx*KXC+kx];
      sr += a.x*c - a.y*s;
      si += a.x*s + a.y*c;
    }
    F2[((size_t)bc*NX + xx)*(KYC*KT) + ky*KT + kt] = make_float2(sr,si);
  }
}

// ------- fused inv-Y + irfft-T + conv1x1 [+gelu], in-place on V -------
// grid = B*NX*2: block = (b, x, y-half of 32). All global access is
// coalesced via LDS staging; fr (F2 slice) + conv weight row in registers.
#define VTS 36
template<bool GELU>
__global__ __launch_bounds__(256,4) void k_inv_y_conv(const float2* __restrict__ F2, const float* __restrict__ wcv,
                                                      const float* __restrict__ bcv, float* __restrict__ Vio){
  __shared__ __align__(16) unsigned char smem[28032];
  float*  vtT0 = (float*)(smem);                 // [40*36]  5760 B
  float*  vtT1 = (float*)(smem + 5760);          // [40*36]
  float*  vtO  = (float*)(smem + 11520);         // [40*36]
  float2* ftc  = (float2*)(smem + 17280);        // [256]    2048 B
  float2* tcts = (float2*)(smem + 19328);        // [8*40]   2560 B
  float2* twy  = (float2*)(smem + 21888);        // [32*24]  6144 B  (end 28032)
  float2* f2h  = (float2*)(smem);                // prologue alias: [16][192] = 24576 B

  int tid = threadIdx.x;
  int b  = blockIdx.x >> 7;
  int x  = (blockIdx.x >> 1) & 63;
  int yb = blockIdx.x & 1;
  int y0 = yb * 32;
  int cid = tid & 31, ktid = tid >> 5;   // inv-Y identity (channel, kt)
  int oid = tid & 31, tg  = tid >> 5;    // conv identity (out-channel, t-group)

  // ---- prologue: stage F2 slice in two halves, extract to registers ----
  float2 fr[KYC];
  #pragma unroll
  for(int half=0; half<2; half++){
    for(int i=tid;i<1536;i+=256){        // 16 rows x 96 float4
      int c=i/96, q=i-c*96;
      ((float4*)f2h)[i] = *((const float4*)(F2 + ((size_t)(b*WID + half*16 + c)*NX + x)*(KYC*KT)) + q);
    }
    __syncthreads();
    if((cid>>4) == half){
      const float2* fp = f2h + (cid&15)*192 + ktid;
      #pragma unroll
      for(int ky=0;ky<KYC;ky++) fr[ky] = fp[ky*8];
    }
    __syncthreads();
  }
  // conv weights -> registers (one-time, 4 KB)
  float wreg[WID];
  #pragma unroll
  for(int c=0;c<WID;c++) wreg[c] = wcv[oid*WID + c];
  float breg = bcv[oid];
  // tables (after f2h is dead)
  for(int i=tid;i<KT*NT;i+=256){
    int k=i/NT, t=i-k*NT;
    float ang = TWO_PI*(float)((k*t)%NT)/(float)NT;
    float sc = (k==0 ? 1.0f : 2.0f)*(1.0f/(float)NT);
    tcts[i] = make_float2(cosf(ang)*sc, sinf(ang)*sc);
  }
  for(int i=tid;i<32*KYC;i+=256){
    int yy=i/KYC, ky=i-yy*KYC;
    int f = ky<M1C ? ky : ky+40;
    float ang = TWO_PI*(float)((f*(y0+yy))%NY)/(float)NY;
    twy[i] = make_float2(cosf(ang)*(1.0f/64.0f), sinf(ang)*(1.0f/64.0f));
  }
  // vt chunk identities: 320 float4 chunks per y; chunk = (c, tq)
  int cc0 = tid/10,        tq0 = tid - (tid/10)*10;
  int cc1 = (256+tid)/10,  tq1 = (256+tid) - ((256+tid)/10)*10;
  bool has2 = tid < 64;
  const float4* gb0 = (const float4*)(Vio + ((size_t)(b*WID+cc0)*NXY + x*NY + y0)*NT) + tq0;
  const float4* gb1 = (const float4*)(Vio + ((size_t)(b*WID+cc1)*NXY + x*NY + y0)*NT) + tq1;
  // prologue fill of vtT0 (y=0)
  float4 g0 = gb0[0];
  float4 g1 = has2 ? gb1[0] : make_float4(0,0,0,0);
  vtT0[(tq0*4+0)*VTS+cc0]=g0.x; vtT0[(tq0*4+1)*VTS+cc0]=g0.y;
  vtT0[(tq0*4+2)*VTS+cc0]=g0.z; vtT0[(tq0*4+3)*VTS+cc0]=g0.w;
  if(has2){
    vtT0[(tq1*4+0)*VTS+cc1]=g1.x; vtT0[(tq1*4+1)*VTS+cc1]=g1.y;
    vtT0[(tq1*4+2)*VTS+cc1]=g1.z; vtT0[(tq1*4+3)*VTS+cc1]=g1.w;
  }
  __syncthreads();

  for(int y=0;y<32;y++){
    // prefetch next y's V rows (kept in flight across barrier_lds)
    if(y+1 < 32){
      g0 = gb0[(size_t)(y+1)*10];
      if(has2) g1 = gb1[(size_t)(y+1)*10];
    }
    // ---- inverse-Y in registers -> ftc[kt][c] ----
    {
      const float2* tw = twy + y*KYC;
      float sr=0.f, si=0.f;
      #pragma unroll
      for(int ky=0;ky<KYC;ky++){
        float2 w = tw[ky];            // broadcast
        float2 a = fr[ky];
        sr += a.x*w.x - a.y*w.y;
        si += a.x*w.y + a.y*w.x;
      }
      ftc[ktid*32 + cid] = make_float2(sr,si);
    }
    barrier_lds();
    // ---- conv1x1 + irfft-T -> vtO[t][c] ----
    {
      float2 fR[KT];
      #pragma unroll
      for(int k=0;k<KT;k++) fR[k] = ftc[k*32 + oid];
      const float* vb = (y&1) ? vtT1 : vtT0;
      #pragma unroll
      for(int j=0;j<5;j++){
        int t = tg*5 + j;
        float a = breg;
        const float* vrow = vb + t*VTS;
        #pragma unroll
        for(int c4=0;c4<WID;c4+=4){
          float4 vv = *(const float4*)(vrow + c4);   // broadcast b128
          a += vv.x*wreg[c4] + vv.y*wreg[c4+1] + vv.z*wreg[c4+2] + vv.w*wreg[c4+3];
        }
        #pragma unroll
        for(int k=0;k<KT;k++){
          float2 w = tcts[k*NT + t];
          a += fR[k].x*w.x - fR[k].y*w.y;
        }
        vtO[t*VTS + oid] = GELU ? gelu_f(a) : a;
      }
    }
    barrier_lds();
    // ---- coalesced store of y + fill vtT[next] from prefetched regs ----
    {
      float4 o0;
      o0.x = vtO[(tq0*4+0)*VTS+cc0]; o0.y = vtO[(tq0*4+1)*VTS+cc0];
      o0.z = vtO[(tq0*4+2)*VTS+cc0]; o0.w = vtO[(tq0*4+3)*VTS+cc0];
      ((float4*)(Vio + ((size_t)(b*WID+cc0)*NXY + x*NY + y0 + y)*NT))[tq0] = o0;
      if(has2){
        float4 o1;
        o1.x = vtO[(tq1*4+0)*VTS+cc1]; o1.y = vtO[(tq1*4+1)*VTS+cc1];
        o1.z = vtO[(tq1*4+2)*VTS+cc1]; o1.w = vtO[(tq1*4+3)*VTS+cc1];
        ((float4*)(Vio + ((size_t)(b*WID+cc1)*NXY + x*NY + y0 + y)*NT))[tq1] = o1;
      }
      if(y+1 < 32){
        float* d = (y&1) ? vtT0 : vtT1;
        d[(tq0*4+0)*VTS+cc0]=g0.x; d[(tq0*4+1)*VTS+cc0]=g0.y;
        d[(tq0*4+2)*VTS+cc0]=g0.z; d[(tq0*4+3)*VTS+cc0]=g0.w;
        if(has2){
          d[(tq1*4+0)*VTS+cc1]=g1.x; d[(tq1*4+1)*VTS+cc1]=g1.y;
          d[(tq1*4+2)*VTS+cc1]=g1.z; d[(tq1*4+3)*VTS+cc1]=g1.w;
        }
      }
    }
    barrier_lds();
  }
}

// ---------------- fused fc1+gelu+fc2: V -> out [B,X,Y,T,2] ----------------
__global__ __launch_bounds__(64) void k_mlp(const float* __restrict__ Vin, const float* __restrict__ w1,
                                            const float* __restrict__ b1, const float* __restrict__ w2,
                                            const float* __restrict__ b2, float* __restrict__ out){
  __shared__ float vt[WID*NT];
  __shared__ float sw1[WID*64];
  __shared__ float sb1[64];
  __shared__ float sw2[128];
  __shared__ float sb2[2];
  int tid=threadIdx.x;
  int b  = blockIdx.x >> 12;
  int xy = blockIdx.x & 4095;
  for(int i=tid;i<WID*NT;i+=64){
    int c=i/NT, t=i-c*NT;
    vt[i] = Vin[((size_t)(b*WID+c))*NXYT + xy*NT + t];
  }
  for(int i=tid;i<WID*64;i+=64) sw1[i]=w1[i];
  sb1[tid]=b1[tid];
  for(int i=tid;i<128;i+=64) sw2[i]=w2[i];
  if(tid<2) sb2[tid]=b2[tid];
  __syncthreads();
  if(tid<NT){
    float vcol[WID];
    #pragma unroll
    for(int c=0;c<WID;c++) vcol[c]=vt[c*NT+tid];
    float o0=sb2[0], o1=sb2[1];
    #pragma unroll 4
    for(int j=0;j<64;j++){
      float a = sb1[j];
      #pragma unroll
      for(int c=0;c<WID;c++) a += vcol[c]*sw1[c*64+j];
      a = gelu_f(a);
      o0 += a*sw2[j*2+0];
      o1 += a*sw2[j*2+1];
    }
    size_t p = ((size_t)(b*NXY + xy))*NT + tid;
    out[p*2+0]=o0;
    out[p*2+1]=o1;
  }
}

extern "C" void kernel_launch(void* const* d_in, const int* in_sizes, int n_in,
                              void* d_out, int out_size, void* d_ws, size_t ws_size,
                              hipStream_t stream){
  const float* h     = (const float*)d_in[0];
  const float* x     = (const float*)d_in[1];
  const float* fc0_w = (const float*)d_in[2];
  const float* fc0_b = (const float*)d_in[3];
  const float* scwr[3] = {(const float*)d_in[4], (const float*)d_in[6], (const float*)d_in[8]};
  const float* scwi[3] = {(const float*)d_in[5], (const float*)d_in[7], (const float*)d_in[9]};
  const float* cw[3]   = {(const float*)d_in[10], (const float*)d_in[12], (const float*)d_in[14]};
  const float* cb[3]   = {(const float*)d_in[11], (const float*)d_in[13], (const float*)d_in[15]};
  const float* fc1_w = (const float*)d_in[16];
  const float* fc1_b = (const float*)d_in[17];
  const float* fc2_w = (const float*)d_in[18];
  const float* fc2_b = (const float*)d_in[19];

  // workspace: V (167.8 MB) | F2 (25.2 MB) | F4 (9.4 MB)  == 202 MB total
  // F3 lives in d_out (9.4 MB <= 10.5 MB) until k_mlp overwrites it at the end.
  const size_t VSZ = (size_t)BATCH*WID*NXYT;          // 41,943,040 floats
  float*  V  = (float*)d_ws;
  float2* F2 = (float2*)(V + VSZ);                    // B*32*64*24*8 = 3,145,728 cplx
  float2* F4 = F2 + (size_t)BATCH*WID*NX*KYC*KT;      // B*32*24*24*8 = 1,179,648 cplx
  float2* F3 = (float2*)d_out;                        // scratch until final k_mlp

  k_fc0<<<NP/256, 256, 0, stream>>>(h, x, fc0_w, fc0_b, V);
  for(int L=0; L<3; L++){
    k_fwd_ty<<<BATCH*WID*NX, 256, 0, stream>>>(V, F2);
    k_fwd_x<<<(BATCH*WID)*KYC, 256, 0, stream>>>(F2, F3);
    k_mix<<<(BATCH*WID*KXC*KYC*KT)/256, 256, 0, stream>>>(F3, scwr[L], scwi[L], F4);
    k_inv_x<<<(BATCH*WID)*KYC, 256, 0, stream>>>(F4, F2);
    if(L<2) k_inv_y_conv<true ><<<BATCH*NX*2, 256, 0, stream>>>(F2, cw[L], cb[L], V);
    else    k_inv_y_conv<false><<<BATCH*NX*2, 256, 0, stream>>>(F2, cw[L], cb[L], V);
  }
  k_mlp<<<BATCH*NXY, 64, 0, stream>>>(V, fc1_w, fc1_b, fc2_w, fc2_b, (float*)d_out);
}